// Round 11
// baseline (45.499 us; speedup 1.0000x reference)
//
#include <hip/hip_runtime.h>

#define S_DIM 4096
#define B_DIM 8
#define LN_EPS 1e-3f

typedef _Float16 half8 __attribute__((ext_vector_type(8)));
typedef _Float16 half4v __attribute__((ext_vector_type(4)));
typedef float f32x4 __attribute__((ext_vector_type(4)));

// ---------------------------------------------------------------------------
// Dispatch 1: blocks 0..1023 = prep (fragment-contiguous wt2),
//   blocks 1024..1535 = banded stage1 (known-good from R5/R9).
// wt2: flat idx = ((a*8 + j)*64 + l)*8 + e  holds W[k][a][c],
//   k=(j>>1)*16+(l&15), c=(j&1)*32+(l>>4)*8+e.  (1KB coalesced per fragment)
// ---------------------------------------------------------------------------
__global__ __launch_bounds__(256) void prep_stage1(const float* __restrict__ x,
                                                   const float* __restrict__ W,
                                                   _Float16* __restrict__ wt2,
                                                   _Float16* __restrict__ s_out) {
    if (blockIdx.x < 1024) {   // ---- prep role ----
        int idx = blockIdx.x * 256 + threadIdx.x;
        int a = idx >> 12;
        int j = (idx >> 9) & 7;
        int l2 = (idx >> 3) & 63;
        int e = idx & 7;
        int k = (j >> 1) * 16 + (l2 & 15);
        int c = (j & 1) * 32 + (l2 >> 4) * 8 + e;
        wt2[idx] = (_Float16)W[((k << 6) + a) * 64 + c];
        return;
    }
    // ---- stage1 role: banded s_pre (d <= 128..192) ----
    const int lin = blockIdx.x - 1024;
    const int it = lin & 63;
    const int by = lin >> 6;
    const int i0 = it * 64;
    const int tid = threadIdx.x;
    const int w = tid >> 6, l = tid & 63, lg = l >> 4, lr = l & 15;

    __shared__ _Float16 Bs[64 * 72];

    f32x4 acc[4] = {};
    const float iRowF = (float)(i0 + w * 16 + lr);
    const int ldC = tid & 63;
    const int ldJ = (tid >> 6) * 16;

    const int jt0 = (it >= 2) ? (it - 2) : 0;
    for (int jt = jt0; jt <= it; ++jt) {
        const int j0 = jt * 64;
        __syncthreads();
        {
            const float* xp = x + ((size_t)by * S_DIM + j0 + ldJ) * 64 + ldC;
            half8 v0, v1;
            #pragma unroll
            for (int q = 0; q < 8; ++q) {
                v0[q] = (_Float16)xp[q * 64];
                v1[q] = (_Float16)xp[(8 + q) * 64];
            }
            *(half8*)&Bs[ldC * 72 + ldJ] = v0;
            *(half8*)&Bs[ldC * 72 + ldJ + 8] = v1;
        }
        __syncthreads();
        #pragma unroll
        for (int kk = 0; kk < 2; ++kk) {
            half8 af;
            #pragma unroll
            for (int bq = 0; bq < 8; ++bq) {
                int j = j0 + kk * 32 + lg * 8 + bq;
                float df = iRowF - (float)j;
                float tv = (df > 0.f) ? __builtin_amdgcn_rcpf(df * df) : 0.f;
                af[bq] = (_Float16)tv;
            }
            #pragma unroll
            for (int nt = 0; nt < 4; ++nt) {
                half8 bf = *(const half8*)&Bs[(nt * 16 + lr) * 72 + kk * 32 + lg * 8];
                acc[nt] = __builtin_amdgcn_mfma_f32_16x16x32_f16(af, bf, acc[nt], 0, 0, 0);
            }
        }
    }

    #pragma unroll
    for (int nt = 0; nt < 4; ++nt)
        #pragma unroll
        for (int r = 0; r < 4; ++r)
            s_out[((size_t)by * S_DIM + i0 + w * 16 + lg * 4 + r) * 64 + nt * 16 + lr]
                = (_Float16)acc[nt][r];
}

// ---------------------------------------------------------------------------
// Stage 2 v9: 128 rows/block, 256 blocks (exactly 1/CU), 512 thr / 8 waves,
//   K-split 8 (wave w: a = w*8+t), R=8 row-tiles/wave. W streams L2->VGPR
//   (fragment-contiguous wt2, ping-pong, barrier-free). s in XOR-swizzled
//   LDS tile; xa in padded LDS tile. Per-CU W traffic: 512 KB, read once.
//   Epilogue: 3-round pairwise tree combine (f16 LDS) + 8-wave LayerNorm.
// ---------------------------------------------------------------------------
__global__ __launch_bounds__(512, 2) void stage2(const float* __restrict__ x,
                                                 const _Float16* __restrict__ s,
                                                 const _Float16* __restrict__ wt2,
                                                 const float* __restrict__ gamma,
                                                 const float* __restrict__ beta,
                                                 float* __restrict__ out) {
    const int r0 = blockIdx.x * 128;
    const int tid = threadIdx.x;
    const int w = tid >> 6, l = tid & 63, lg = l >> 4, lr = l & 15;

    __shared__ __align__(16) char smem[69632];
    _Float16* sT = (_Float16*)smem;                 // [128][64] f16, slot-XOR-swizzled
    _Float16* xT = (_Float16*)(smem + 16384);       // [128][72] f16
    // tree buffers (overlay, used after K-loop): TB(q) = [128][68] f16

#define TB(q_) ((_Float16*)(smem + (q_) * 17408))

    // this wave's W stream: 8 slices x 8KB, lane-sliced by l*16
    const char* mylane = (const char*)wt2 + ((size_t)w << 16) + l * 16;

    half8 bA[4][2], bB[4][2];
#define PREF(BUF, t_)                                                          \
    {                                                                          \
        _Pragma("unroll")                                                      \
        for (int f_ = 0; f_ < 8; ++f_)                                         \
            (&BUF[0][0])[f_] =                                                 \
                *(const half8*)(mylane + (size_t)(t_) * 8192 + f_ * 1024);     \
    }

    PREF(bA, 0);   // issue W slice 0 first (L2 latency under tile staging)

    {   // stage sT (swizzled) and xT: 1024 slots of 8 c-elems, 2 per thread
        #pragma unroll
        for (int h = 0; h < 2; ++h) {
            int slot = h * 512 + tid;
            int row = slot >> 3, c0 = (slot & 7) * 8;
            half8 sv = *(const half8*)&s[(size_t)(r0 + row) * 64 + c0];
            *(half8*)&sT[row * 64 + ((((c0 >> 3) ^ (row & 7))) << 3)] = sv;
            const float* xp = x + (size_t)(r0 + row) * 64 + c0;
            float4 v0 = *(const float4*)xp;
            float4 v1 = *(const float4*)(xp + 4);
            half8 hv;
            hv[0] = (_Float16)v0.x; hv[1] = (_Float16)v0.y;
            hv[2] = (_Float16)v0.z; hv[3] = (_Float16)v0.w;
            hv[4] = (_Float16)v1.x; hv[5] = (_Float16)v1.y;
            hv[6] = (_Float16)v1.z; hv[7] = (_Float16)v1.w;
            *(half8*)&xT[row * 72 + c0] = hv;
        }
    }
    __syncthreads();

    const int sw0 = ((lg ^ (lr & 7)) << 3);
    const int sw1 = (((4 + lg) ^ (lr & 7)) << 3);

    f32x4 acc[8][4] = {};

#define CLUSTER(BUF, t_)                                                       \
    {                                                                          \
        _Pragma("unroll")                                                      \
        for (int rt_ = 0; rt_ < 8; ++rt_) {                                    \
            const int row_ = rt_ * 16 + lr;                                    \
            _Float16 xa = xT[row_ * 72 + w * 8 + (t_)];                        \
            half8 s0 = *(const half8*)&sT[row_ * 64 + sw0];                    \
            half8 s1 = *(const half8*)&sT[row_ * 64 + sw1];                    \
            half8 af0 = s0 * xa;                                               \
            half8 af1 = s1 * xa;                                               \
            _Pragma("unroll")                                                  \
            for (int nt_ = 0; nt_ < 4; ++nt_) {                                \
                acc[rt_][nt_] = __builtin_amdgcn_mfma_f32_16x16x32_f16(        \
                    af0, BUF[nt_][0], acc[rt_][nt_], 0, 0, 0);                 \
                acc[rt_][nt_] = __builtin_amdgcn_mfma_f32_16x16x32_f16(        \
                    af1, BUF[nt_][1], acc[rt_][nt_], 0, 0, 0);                 \
            }                                                                  \
        }                                                                      \
    }

    #pragma unroll
    for (int tt = 0; tt < 4; ++tt) {
        const int t0 = tt * 2;
        PREF(bB, t0 + 1);                    // in flight during cluster t0
        CLUSTER(bA, t0);
        if (t0 + 2 < 8) PREF(bA, t0 + 2);    // in flight during cluster t0+1
        CLUSTER(bB, t0 + 1);
    }
#undef PREF
#undef CLUSTER

    // ---- pairwise-tree K-split combine (f16 partials through LDS) ----
#define WRITEP(q_)                                                             \
    {                                                                          \
        _Float16* P_ = TB(q_);                                                 \
        _Pragma("unroll")                                                      \
        for (int rt_ = 0; rt_ < 8; ++rt_)                                      \
            _Pragma("unroll")                                                  \
            for (int nt_ = 0; nt_ < 4; ++nt_)                                  \
                _Pragma("unroll")                                              \
                for (int rg_ = 0; rg_ < 4; ++rg_)                              \
                    P_[(rt_ * 16 + lg * 4 + rg_) * 68 + nt_ * 16 + lr] =       \
                        (_Float16)acc[rt_][nt_][rg_];                          \
    }
#define ADDP(q_)                                                               \
    {                                                                          \
        const _Float16* P_ = TB(q_);                                           \
        _Pragma("unroll")                                                      \
        for (int rt_ = 0; rt_ < 8; ++rt_)                                      \
            _Pragma("unroll")                                                  \
            for (int nt_ = 0; nt_ < 4; ++nt_)                                  \
                _Pragma("unroll")                                              \
                for (int rg_ = 0; rg_ < 4; ++rg_)                              \
                    acc[rt_][nt_][rg_] +=                                      \
                        (float)P_[(rt_ * 16 + lg * 4 + rg_) * 68 + nt_ * 16 + lr]; \
    }

    __syncthreads();                 // sT/xT dead; safe to overlay tree buffers
    if (w >= 4) WRITEP(w - 4);
    __syncthreads();
    if (w < 4) ADDP(w);
    __syncthreads();
    if (w == 2 || w == 3) WRITEP(w - 2);
    __syncthreads();
    if (w < 2) ADDP(w);
    __syncthreads();
    if (w == 1) WRITEP(0);
    __syncthreads();
    if (w == 0) { ADDP(0); WRITEP(1); }   // full sum -> TB(1)
    __syncthreads();
#undef WRITEP
#undef ADDP

    // ---- LayerNorm: wave w handles rows [w*16, w*16+16); 4 lanes/row ----
    {
        const int row = w * 16 + (l >> 2);
        const int q = l & 3;
        const _Float16* F = TB(1) + row * 68 + q * 16;
        const float* xr = x + (size_t)(r0 + row) * 64 + q * 16;
        float v[16];
        #pragma unroll
        for (int j = 0; j < 4; ++j) {
            half4v hv = *(const half4v*)&F[j * 4];
            float4 xv = *(const float4*)&xr[j * 4];
            v[j * 4 + 0] = (float)hv[0] + xv.x;
            v[j * 4 + 1] = (float)hv[1] + xv.y;
            v[j * 4 + 2] = (float)hv[2] + xv.z;
            v[j * 4 + 3] = (float)hv[3] + xv.w;
        }
        float s_ = 0.f, q2 = 0.f;
        #pragma unroll
        for (int i = 0; i < 16; ++i) { s_ += v[i]; q2 += v[i] * v[i]; }
        s_ += __shfl_xor(s_, 1, 64);  q2 += __shfl_xor(q2, 1, 64);
        s_ += __shfl_xor(s_, 2, 64);  q2 += __shfl_xor(q2, 2, 64);
        const float mean = s_ * (1.f / 64.f);
        const float var = q2 * (1.f / 64.f) - mean * mean;
        const float rstd = __frsqrt_rn(var + LN_EPS);
        float* op = out + (size_t)(r0 + row) * 64 + q * 16;
        #pragma unroll
        for (int j = 0; j < 4; ++j) {
            float4 g = *(const float4*)&gamma[q * 16 + j * 4];
            float4 b = *(const float4*)&beta[q * 16 + j * 4];
            float4 o;
            o.x = (v[j * 4 + 0] - mean) * rstd * g.x + b.x;
            o.y = (v[j * 4 + 1] - mean) * rstd * g.y + b.y;
            o.z = (v[j * 4 + 2] - mean) * rstd * g.z + b.z;
            o.w = (v[j * 4 + 3] - mean) * rstd * g.w + b.w;
            *(float4*)&op[j * 4] = o;
        }
    }
#undef TB
}

// ---------------------------------------------------------------------------
extern "C" void kernel_launch(void* const* d_in, const int* in_sizes, int n_in,
                              void* d_out, int out_size, void* d_ws, size_t ws_size,
                              hipStream_t stream) {
    const float* x     = (const float*)d_in[0];
    const float* W     = (const float*)d_in[1];
    const float* gamma = (const float*)d_in[2];
    const float* beta  = (const float*)d_in[3];
    float* outp        = (float*)d_out;

    char* ws = (char*)d_ws;
    _Float16* s_f16 = (_Float16*)ws;                                    // 4 MB
    _Float16* wt2   = (_Float16*)(ws + (size_t)B_DIM * S_DIM * 64 * 2); // 512 KB

    prep_stage1<<<1536, 256, 0, stream>>>(x, W, wt2, s_f16);
    stage2<<<(B_DIM * S_DIM) / 128, 512, 0, stream>>>(x, s_f16, wt2, gamma, beta, outp);
}

// Round 12
// 35.388 us; speedup vs baseline: 1.2857x; 1.2857x over previous
//
#include <hip/hip_runtime.h>

#define S_DIM 4096
#define B_DIM 8
#define LN_EPS 1e-3f

typedef _Float16 half8 __attribute__((ext_vector_type(8)));
typedef _Float16 half2v __attribute__((ext_vector_type(2)));
typedef float f32x4 __attribute__((ext_vector_type(4)));

// ---------------------------------------------------------------------------
// Dispatch 1: blocks 0..1023 = prep (fragment-contiguous wt2),
//   blocks 1024..1535 = banded stage1 (known-good from R5/R9).
// wt2: flat idx = ((a*8 + j)*64 + l)*8 + e  holds W[k][a][c],
//   k=(j>>1)*16+(l&15), c=(j&1)*32+(l>>4)*8+e.  (1KB coalesced per fragment)
// ---------------------------------------------------------------------------
__global__ __launch_bounds__(256) void prep_stage1(const float* __restrict__ x,
                                                   const float* __restrict__ W,
                                                   _Float16* __restrict__ wt2,
                                                   _Float16* __restrict__ s_out) {
    if (blockIdx.x < 1024) {   // ---- prep role ----
        int idx = blockIdx.x * 256 + threadIdx.x;
        int a = idx >> 12;
        int j = (idx >> 9) & 7;
        int l2 = (idx >> 3) & 63;
        int e = idx & 7;
        int k = (j >> 1) * 16 + (l2 & 15);
        int c = (j & 1) * 32 + (l2 >> 4) * 8 + e;
        wt2[idx] = (_Float16)W[((k << 6) + a) * 64 + c];
        return;
    }
    // ---- stage1 role: banded s_pre (d <= 128..192) ----
    const int lin = blockIdx.x - 1024;
    const int it = lin & 63;
    const int by = lin >> 6;
    const int i0 = it * 64;
    const int tid = threadIdx.x;
    const int w = tid >> 6, l = tid & 63, lg = l >> 4, lr = l & 15;

    __shared__ _Float16 Bs[64 * 72];

    f32x4 acc[4] = {};
    const float iRowF = (float)(i0 + w * 16 + lr);
    const int ldC = tid & 63;
    const int ldJ = (tid >> 6) * 16;

    const int jt0 = (it >= 2) ? (it - 2) : 0;
    for (int jt = jt0; jt <= it; ++jt) {
        const int j0 = jt * 64;
        __syncthreads();
        {
            const float* xp = x + ((size_t)by * S_DIM + j0 + ldJ) * 64 + ldC;
            half8 v0, v1;
            #pragma unroll
            for (int q = 0; q < 8; ++q) {
                v0[q] = (_Float16)xp[q * 64];
                v1[q] = (_Float16)xp[(8 + q) * 64];
            }
            *(half8*)&Bs[ldC * 72 + ldJ] = v0;
            *(half8*)&Bs[ldC * 72 + ldJ + 8] = v1;
        }
        __syncthreads();
        #pragma unroll
        for (int kk = 0; kk < 2; ++kk) {
            half8 af;
            #pragma unroll
            for (int bq = 0; bq < 8; ++bq) {
                int j = j0 + kk * 32 + lg * 8 + bq;
                float df = iRowF - (float)j;
                float tv = (df > 0.f) ? __builtin_amdgcn_rcpf(df * df) : 0.f;
                af[bq] = (_Float16)tv;
            }
            #pragma unroll
            for (int nt = 0; nt < 4; ++nt) {
                half8 bf = *(const half8*)&Bs[(nt * 16 + lr) * 72 + kk * 32 + lg * 8];
                acc[nt] = __builtin_amdgcn_mfma_f32_16x16x32_f16(af, bf, acc[nt], 0, 0, 0);
            }
        }
    }

    #pragma unroll
    for (int nt = 0; nt < 4; ++nt)
        #pragma unroll
        for (int r = 0; r < 4; ++r)
            s_out[((size_t)by * S_DIM + i0 + w * 16 + lg * 4 + r) * 64 + nt * 16 + lr]
                = (_Float16)acc[nt][r];
}

// ---------------------------------------------------------------------------
// Stage 2 v10: 128 rows/block, 256 blocks (1/CU), 512 thr = 8 waves
//   = 2 row-groups x 4 a-quarters. R=4 row-tiles/wave (acc=64 VGPR).
//   W streams L2->VGPR (fragment-contiguous wt2, ping-pong, NO LDS, NO
//   barriers in K-loop). W crosses L1 once per rg-pair (~lockstep reuse).
//   Epilogue: single f16 partial round through LDS (49KB), one barrier,
//   ah==0 waves combine + residual + LayerNorm their 64-row half.
// ---------------------------------------------------------------------------
__global__ __launch_bounds__(512, 2) void stage2(const float* __restrict__ x,
                                                 const _Float16* __restrict__ s,
                                                 const _Float16* __restrict__ wt2,
                                                 const float* __restrict__ gamma,
                                                 const float* __restrict__ beta,
                                                 float* __restrict__ out) {
    const int r0 = blockIdx.x * 128;
    const int tid = threadIdx.x;
    const int w = tid >> 6, l = tid & 63, lg = l >> 4, lr = l & 15;
    const int rg = w & 1;          // row half: rows [r0 + rg*64, +64)
    const int ah = w >> 1;         // a-quarter: a = ah*16 + t
    const int rbase = r0 + rg * 64;

    // 6 partial buffers (2 rg x 3 ph), acc-layout lane-contiguous half2v
    __shared__ __align__(16) half2v Pf[12288];     // 49 KB

    // this wave's W stream: 16 slices x 8KB, lane-sliced by l*16
    const char* mylane = (const char*)wt2 + ((size_t)ah << 17) + l * 16;

    // s fragments and xa scalars for this wave's 4 row-tiles
    half8 sf[4][2];
    #pragma unroll
    for (int rt = 0; rt < 4; ++rt) {
        size_t row = (size_t)(rbase + rt * 16 + lr) * 64;
        sf[rt][0] = *(const half8*)&s[row + lg * 8];
        sf[rt][1] = *(const half8*)&s[row + 32 + lg * 8];
    }
    half8 xav[4][2];
    #pragma unroll
    for (int rt = 0; rt < 4; ++rt) {
        const float* xp = x + (size_t)(rbase + rt * 16 + lr) * 64 + ah * 16;
        half8 h0, h1;
        #pragma unroll
        for (int j = 0; j < 8; ++j) {
            h0[j] = (_Float16)xp[j];
            h1[j] = (_Float16)xp[8 + j];
        }
        xav[rt][0] = h0;
        xav[rt][1] = h1;
    }

    half8 bA[4][2], bB[4][2];   // [nt][c-half]; frag f = nt*2 + h

#define PREF(BUF, t_)                                                          \
    {                                                                          \
        _Pragma("unroll")                                                      \
        for (int f_ = 0; f_ < 8; ++f_)                                         \
            (&BUF[0][0])[f_] =                                                 \
                *(const half8*)(mylane + (size_t)(t_) * 8192 + f_ * 1024);     \
    }
#define CLUSTER(BUF, t_)                                                       \
    {                                                                          \
        _Pragma("unroll")                                                      \
        for (int rt_ = 0; rt_ < 4; ++rt_) {                                    \
            _Float16 xa = xav[rt_][(t_) >> 3][(t_) & 7];                       \
            half8 af0 = sf[rt_][0] * xa;                                       \
            half8 af1 = sf[rt_][1] * xa;                                       \
            _Pragma("unroll")                                                  \
            for (int nt_ = 0; nt_ < 4; ++nt_) {                                \
                acc[rt_][nt_] = __builtin_amdgcn_mfma_f32_16x16x32_f16(        \
                    af0, BUF[nt_][0], acc[rt_][nt_], 0, 0, 0);                 \
                acc[rt_][nt_] = __builtin_amdgcn_mfma_f32_16x16x32_f16(        \
                    af1, BUF[nt_][1], acc[rt_][nt_], 0, 0, 0);                 \
            }                                                                  \
        }                                                                      \
    }

    f32x4 acc[4][4] = {};
    PREF(bA, 0);
    #pragma unroll
    for (int tt = 0; tt < 8; ++tt) {
        const int t0 = tt * 2;
        PREF(bB, t0 + 1);                    // in flight during cluster t0
        CLUSTER(bA, t0);
        if (t0 + 2 < 16) PREF(bA, t0 + 2);   // in flight during cluster t0+1
        CLUSTER(bB, t0 + 1);
    }
#undef PREF
#undef CLUSTER

    // ---- epilogue: ah!=0 waves dump f16 partials, one barrier,
    //      ah==0 waves combine + residual + LayerNorm ----
    if (ah != 0) {
        const int q = rg * 3 + (ah - 1);     // 0..5
        #pragma unroll
        for (int rt = 0; rt < 4; ++rt)
            #pragma unroll
            for (int nt = 0; nt < 4; ++nt) {
                int base = (((q * 4 + rt) * 4 + nt) * 2) * 64 + l;
                half2v p01 = { (_Float16)acc[rt][nt][0], (_Float16)acc[rt][nt][1] };
                half2v p23 = { (_Float16)acc[rt][nt][2], (_Float16)acc[rt][nt][3] };
                Pf[base] = p01;
                Pf[base + 64] = p23;
            }
    }
    __syncthreads();

    if (ah == 0) {
        float gba[4], bta[4];
        #pragma unroll
        for (int nt = 0; nt < 4; ++nt) {
            gba[nt] = gamma[nt * 16 + lr];
            bta[nt] = beta[nt * 16 + lr];
        }
        #pragma unroll
        for (int rt = 0; rt < 4; ++rt) {
            float rv[4][4], sum[4], ssq[4];
            #pragma unroll
            for (int nt = 0; nt < 4; ++nt) {
                float v0 = acc[rt][nt][0], v1 = acc[rt][nt][1];
                float v2 = acc[rt][nt][2], v3 = acc[rt][nt][3];
                #pragma unroll
                for (int ph = 0; ph < 3; ++ph) {
                    int q = rg * 3 + ph;
                    int base = (((q * 4 + rt) * 4 + nt) * 2) * 64 + l;
                    half2v q01 = Pf[base];
                    half2v q23 = Pf[base + 64];
                    v0 += (float)q01[0]; v1 += (float)q01[1];
                    v2 += (float)q23[0]; v3 += (float)q23[1];
                }
                acc[rt][nt][0] = v0; acc[rt][nt][1] = v1;
                acc[rt][nt][2] = v2; acc[rt][nt][3] = v3;
            }
            #pragma unroll
            for (int reg = 0; reg < 4; ++reg) {
                const int row_l = rt * 16 + lg * 4 + reg;
                const float* xr = x + (size_t)(rbase + row_l) * 64;
                float s_ = 0.f, q_ = 0.f;
                #pragma unroll
                for (int nt = 0; nt < 4; ++nt) {
                    float v = acc[rt][nt][reg] + xr[nt * 16 + lr];
                    rv[nt][reg] = v;
                    s_ += v;
                    q_ += v * v;
                }
                sum[reg] = s_;
                ssq[reg] = q_;
            }
            #pragma unroll
            for (int m = 1; m < 16; m <<= 1) {
                #pragma unroll
                for (int reg = 0; reg < 4; ++reg) {
                    sum[reg] += __shfl_xor(sum[reg], m, 64);
                    ssq[reg] += __shfl_xor(ssq[reg], m, 64);
                }
            }
            #pragma unroll
            for (int reg = 0; reg < 4; ++reg) {
                float mean = sum[reg] * (1.f / 64.f);
                float var = ssq[reg] * (1.f / 64.f) - mean * mean;
                float rstd = __frsqrt_rn(var + LN_EPS);
                const int gr = rbase + rt * 16 + lg * 4 + reg;
                #pragma unroll
                for (int nt = 0; nt < 4; ++nt) {
                    float y = (rv[nt][reg] - mean) * rstd * gba[nt] + bta[nt];
                    out[(size_t)gr * 64 + nt * 16 + lr] = y;
                }
            }
        }
    }
}

// ---------------------------------------------------------------------------
extern "C" void kernel_launch(void* const* d_in, const int* in_sizes, int n_in,
                              void* d_out, int out_size, void* d_ws, size_t ws_size,
                              hipStream_t stream) {
    const float* x     = (const float*)d_in[0];
    const float* W     = (const float*)d_in[1];
    const float* gamma = (const float*)d_in[2];
    const float* beta  = (const float*)d_in[3];
    float* outp        = (float*)d_out;

    char* ws = (char*)d_ws;
    _Float16* s_f16 = (_Float16*)ws;                                    // 4 MB
    _Float16* wt2   = (_Float16*)(ws + (size_t)B_DIM * S_DIM * 64 * 2); // 512 KB

    prep_stage1<<<1536, 256, 0, stream>>>(x, W, wt2, s_f16);
    stage2<<<(B_DIM * S_DIM) / 128, 512, 0, stream>>>(x, s_f16, wt2, gamma, beta, outp);
}